// Round 1
// baseline (234.626 us; speedup 1.0000x reference)
//
#include <hip/hip_runtime.h>
#include <hip/hip_bf16.h>

#define DIM 128
#define NROT 8128
#define SPLIT 38            // fans 0..37 -> group0 ; fans 38..126 -> group1
#define NP0 19              // pairs in group0 (i1 = 0,2,...,36)
#define NP1 45              // pairs in group1 (i1 = 38,40,...,126; last pair's 2nd fan empty)
#define E0 2071             // float4 entries in group0 stream
#define E1 2025             // float4 entries in group1 stream
// ws layout (bytes):
//   [0,      65536)  cs pair-stream: 4096 float4 (c1,s1,c2,s2), group0 then group1
//   [65536, 131072)  A0 fp32 [128][128]
//   [131072,163472)  A1 fp32 [90][90]   (global rows/cols 38..127)
//   [163840,196608)  Mb bf16 [128][128] row-major: Mb[c][k] = bf16(M[c][k])

typedef __attribute__((ext_vector_type(4))) float f32x4;
typedef __attribute__((ext_vector_type(8))) short bf16x8;

__device__ __forceinline__ unsigned short f2bf(float f) {
  union { float f; unsigned int u; } v; v.f = f;
  unsigned int u = v.u;
  return (unsigned short)((u + 0x7FFFu + ((u >> 16) & 1u)) >> 16);
}

// ---------------- K1+K2 fused: sincos pair-stream + two-group fan build ----------------
__global__ __launch_bounds__(256) void k_build(const float* __restrict__ angles,
                                               float* __restrict__ ws) {
  __shared__ float lds0[DIM * DIM];   // 64 KB, group0 product A0
  __shared__ float lds1[90 * 90];     // 32.4 KB, group1 product A1 (local idx = global-38)
  const int t = threadIdx.x;

  // ---- prologue: compute (c,s) for every rotation into the packed pair-stream ----
  for (int r0 = t; r0 < NROT; r0 += 256) {
    // invert triangular index: largest i with T(i) <= r0, T(i) = 127 i - i(i-1)/2
    int i = (int)floorf((255.0f - sqrtf(65025.0f - 8.0f * (float)r0)) * 0.5f);
    if (i < 0) i = 0; if (i > 126) i = 126;
    while (127 * (i + 1) - ((i + 1) * i) / 2 <= r0) ++i;
    while (127 * i - (i * (i - 1)) / 2 > r0) --i;
    const int Ti = 127 * i - (i * (i - 1)) / 2;
    const int j  = i + 1 + (r0 - Ti);
    const int g    = (i < SPLIT) ? 0 : 1;
    const int lo   = g ? SPLIT : 0;
    const int b4   = g ? E0 : 0;
    const int p    = (i - lo) >> 1;
    const int sec  = (i - lo) & 1;
    const int i1   = lo + 2 * p;
    const int entry = j - i1 - 1;
    const int off4 = b4 + p * (DIM - lo) - p * p + entry;
    float s, c;
    __sincosf(angles[r0], &s, &c);
    float2 v; v.x = c; v.y = s;
    *(float2*)(ws + off4 * 4 + sec * 2) = v;
  }
  __syncthreads();   // cs stream (global) must be visible to all waves

  // ---- pair-merged fan build; each thread owns one COLUMN -> no barriers needed ----
  const bool g0 = (t < DIM);
  if (t < DIM + 90) {
    float* L; int c, ld, nloc, npairs, base4, span;
    if (g0) { L = lds0; c = t;       ld = DIM; nloc = DIM; npairs = NP0; base4 = 0;  span = DIM;      }
    else    { L = lds1; c = t - DIM; ld = 90;  nloc = 90;  npairs = NP1; base4 = E0; span = DIM - SPLIT; }
    for (int r = 0; r < nloc; ++r) L[r * ld + c] = (r == c) ? 1.0f : 0.0f;
    const float4* cs4 = (const float4*)ws;
    for (int p = 0; p < npairs; ++p) {
      const int i1l = 2 * p;
      const int eb  = base4 + p * span - p * p;
      float r1 = L[i1l * ld + c];
      // peeled first step: single rotation (i1, i1+1)
      float4 e = cs4[eb];
      float rj = L[(i1l + 1) * ld + c];
      float w  = fmaf(e.y, r1, e.x * rj);
      r1 = fmaf(e.x, r1, -(e.y * rj));
      float r2 = w;                       // row i1+1 carried in register for the pair
      #pragma unroll 4
      for (int jl = i1l + 2; jl < nloc; ++jl) {
        const float4 ee = cs4[eb + (jl - i1l - 1)];
        const float rjv = L[jl * ld + c];
        const float t1 = ee.x * rjv;
        const float wv = fmaf(ee.y, r1, t1);        // rot1: new row j
        const float t2 = ee.y * rjv;
        r1 = fmaf(ee.x, r1, -t2);                   // rot1: new row i1
        const float u1 = ee.z * wv;
        const float w2 = fmaf(ee.w, r2, u1);        // rot2: new row j
        const float u2 = ee.w * wv;
        r2 = fmaf(ee.z, r2, -u2);                   // rot2: new row i2
        L[jl * ld + c] = w2;
      }
      L[i1l * ld + c] = r1;
      L[(i1l + 1) * ld + c] = r2;
    }
    // write group product to ws (coalesced across threads per row)
    if (g0) {
      float* A0 = ws + 16384;
      for (int r = 0; r < DIM; ++r) A0[r * DIM + c] = L[r * DIM + c];
    } else {
      float* A1 = ws + 32768;
      for (int r = 0; r < 90; ++r) A1[r * 90 + c] = L[r * 90 + c];
    }
  }
}

// ---------------- K3: M = A1*A0, emit bf16 ----------------
__global__ __launch_bounds__(256) void k_combine(float* __restrict__ ws) {
  const int idx = blockIdx.x * 256 + threadIdx.x;   // 64 blocks * 256 = 16384
  const int r = idx >> 7, cc = idx & 127;
  const float* A0 = ws + 16384;
  const float* A1 = ws + 32768;
  unsigned short* Mb = (unsigned short*)((char*)ws + 163840);
  float v;
  if (r < SPLIT) {
    v = A0[r * DIM + cc];
  } else {
    const int lr = r - SPLIT;
    float acc = 0.0f;
    #pragma unroll 6
    for (int k = 0; k < 90; ++k)
      acc = fmaf(A1[lr * 90 + k], A0[(SPLIT + k) * DIM + cc], acc);
    v = acc;
  }
  Mb[r * DIM + cc] = f2bf(v);
}

// ---------------- K4: out = X @ M^T + bias  (bf16 MFMA, no LDS) ----------------
__global__ __launch_bounds__(256) void k_gemm(const float* __restrict__ X,
                                              const float* __restrict__ bias,
                                              const unsigned short* __restrict__ Mb,
                                              float* __restrict__ out) {
  const int lane = threadIdx.x & 63;
  const int wid  = threadIdx.x >> 6;           // 4 waves/block
  const int l15  = lane & 15, lhi = lane >> 4; // row-in-tile, k-quarter
  const int rowbase = blockIdx.x * 128 + wid * 32;

  f32x4 acc[2][8];
  #pragma unroll
  for (int m = 0; m < 2; ++m)
    #pragma unroll
    for (int n = 0; n < 8; ++n) acc[m][n] = (f32x4){0.f, 0.f, 0.f, 0.f};

  // A fragments: lane holds X[row = rowbase+mt*16+l15][k = kt*32 + lhi*8 + 0..7]
  bf16x8 a[2][4];
  #pragma unroll
  for (int mt = 0; mt < 2; ++mt) {
    const float* xp = X + (rowbase + mt * 16 + l15) * DIM + lhi * 8;
    #pragma unroll
    for (int kt = 0; kt < 4; ++kt) {
      const f32x4 x0 = *(const f32x4*)(xp + kt * 32);
      const f32x4 x1 = *(const f32x4*)(xp + kt * 32 + 4);
      bf16x8 av;
      av[0] = (short)f2bf(x0[0]); av[1] = (short)f2bf(x0[1]);
      av[2] = (short)f2bf(x0[2]); av[3] = (short)f2bf(x0[3]);
      av[4] = (short)f2bf(x1[0]); av[5] = (short)f2bf(x1[1]);
      av[6] = (short)f2bf(x1[2]); av[7] = (short)f2bf(x1[3]);
      a[mt][kt] = av;
    }
  }

  // B fragments from L2-resident Mb: B[k][col=c] = M[c][k] = Mb[c*128+k]
  #pragma unroll
  for (int kt = 0; kt < 4; ++kt) {
    #pragma unroll
    for (int n = 0; n < 8; ++n) {
      const bf16x8 b = *(const bf16x8*)(Mb + ((l15 + 16 * n) * DIM + kt * 32 + lhi * 8));
      acc[0][n] = __builtin_amdgcn_mfma_f32_16x16x32_bf16(a[0][kt], b, acc[0][n], 0, 0, 0);
      acc[1][n] = __builtin_amdgcn_mfma_f32_16x16x32_bf16(a[1][kt], b, acc[1][n], 0, 0, 0);
    }
  }

  // epilogue: C/D layout col = l15, row = lhi*4 + j  (guide §3, m89-verified)
  #pragma unroll
  for (int n = 0; n < 8; ++n) {
    const float bs = bias[16 * n + l15];
    #pragma unroll
    for (int mt = 0; mt < 2; ++mt) {
      const int rb = rowbase + mt * 16 + lhi * 4;
      #pragma unroll
      for (int j = 0; j < 4; ++j)
        out[(rb + j) * DIM + 16 * n + l15] = acc[mt][n][j] + bs;
    }
  }
}

extern "C" void kernel_launch(void* const* d_in, const int* in_sizes, int n_in,
                              void* d_out, int out_size, void* d_ws, size_t ws_size,
                              hipStream_t stream) {
  const float* x      = (const float*)d_in[0];
  const float* angles = (const float*)d_in[1];
  const float* bias   = (const float*)d_in[2];
  float* out = (float*)d_out;
  float* ws  = (float*)d_ws;

  k_build<<<1, 256, 0, stream>>>(angles, ws);
  k_combine<<<64, 256, 0, stream>>>(ws);
  const unsigned short* Mb = (const unsigned short*)((const char*)d_ws + 163840);
  k_gemm<<<1024, 256, 0, stream>>>(x, bias, Mb, out);
}

// Round 2
// 129.571 us; speedup vs baseline: 1.8108x; 1.8108x over previous
//
#include <hip/hip_runtime.h>
#include <hip/hip_bf16.h>

#define DIM 128
#define NROT 8128
// fan groups: g0 = fans [0,24), g1 = [24,52), g2 = [52,127)
// ws layout (floats): A0 [0,16384) 128x128 ; A1 [16384,27200) 104x104 ; A2 [27200,32976) 76x76
// Mb (bf16 of M, row-major [128][128]) at byte offset 131904; total ws use 164672 B.

typedef __attribute__((ext_vector_type(4))) float f32x4;
typedef __attribute__((ext_vector_type(8))) short bf16x8;

__device__ __forceinline__ unsigned short f2bf(float f) {
  union { float f; unsigned int u; } v; v.f = f;
  unsigned int u = v.u;
  return (unsigned short)((u + 0x7FFFu + ((u >> 16) & 1u)) >> 16);
}

// ---- K1: three concurrent group products (block g = fan group g) ----
__global__ __launch_bounds__(256) void k_build(const float* __restrict__ angles,
                                               float* __restrict__ ws) {
  __shared__ float  L[DIM * DIM];   // 64 KB: group product, column c owned by thread c
  __shared__ float4 cs[1444];       // 23.1 KB: pair-merged (c1,s1,c2,s2) stream for THIS group
  const int g    = blockIdx.x;
  const int lo   = (g == 0) ? 0 : (g == 1) ? 24 : 52;
  const int n    = DIM - lo;                         // 128 / 104 / 76
  const int P    = (g == 0) ? 12 : (g == 1) ? 14 : 38;   // fan pairs
  const int rbeg = (g == 0) ? 0 : (g == 1) ? 2772 : 5278;
  const int rend = (g == 0) ? 2772 : (g == 1) ? 5278 : 8128;
  const int aoff = (g == 0) ? 0 : (g == 1) ? 16384 : 27200;
  const int t = threadIdx.x;

  // prologue: sincos for this group's rotations, packed pair-stream in LDS
  for (int r0 = rbeg + t; r0 < rend; r0 += 256) {
    int i = (int)floorf((255.0f - sqrtf(65025.0f - 8.0f * (float)r0)) * 0.5f);
    if (i < 0) i = 0; if (i > 126) i = 126;
    while (127 * (i + 1) - ((i + 1) * i) / 2 <= r0) ++i;
    while (127 * i - (i * (i - 1)) / 2 > r0) --i;
    const int Ti = 127 * i - (i * (i - 1)) / 2;
    const int j  = i + 1 + (r0 - Ti);
    const int fl = i - lo;                 // local fan
    const int p = fl >> 1, sec = fl & 1;
    const int entry = (j - lo) - 2 * p - 1;
    const int off = p * (n - p) + entry;   // pair p stream base = p*(n-p)
    float s, c; __sincosf(angles[r0], &s, &c);
    float2 v; v.x = c; v.y = s;
    *((float2*)&cs[off] + sec) = v;
  }
  __syncthreads();

  if (t < n) {
    const int c = t;
    for (int r = 0; r < n; ++r) L[r * n + c] = (r == c) ? 1.0f : 0.0f;
    for (int p = 0; p < P; ++p) {
      const int i1 = 2 * p;
      const int pb = p * (n - p);
      // peeled: single rotation (i1, i1+1)
      const float4 e0 = cs[pb];
      float r1 = L[i1 * n + c];
      float rj = L[(i1 + 1) * n + c];
      float r2 = fmaf(e0.y, r1, e0.x * rj);
      r1 = fmaf(e0.x, r1, -(e0.y * rj));
      #pragma unroll 8
      for (int jl = i1 + 2; jl < n; ++jl) {
        const float4 e  = cs[pb + (jl - i1 - 1)];
        const float rv  = L[jl * n + c];
        const float wv  = fmaf(e.y, r1, e.x * rv);   // rot1 new row j
        r1 = fmaf(e.x, r1, -(e.y * rv));             // rot1 new row i1 (the only loop-carried dep)
        L[jl * n + c] = fmaf(e.w, r2, e.z * wv);     // rot2 new row j
        r2 = fmaf(e.z, r2, -(e.w * wv));             // rot2 new row i1+1
      }
      L[i1 * n + c] = r1;
      L[(i1 + 1) * n + c] = r2;
    }
    float* A = ws + aoff;
    for (int r = 0; r < n; ++r) A[r * n + c] = L[r * n + c];  // coalesced
  }
}

// ---- K2: M = A2*A1*A0 (fp32, P1 columns staged in LDS), emit bf16 ----
__global__ __launch_bounds__(256) void k_combine(const float* __restrict__ ws,
                                                 unsigned short* __restrict__ Mb) {
  __shared__ float p1[DIM * 2];           // P1[k][c] for this block's 2 columns
  const int t = threadIdx.x;
  const int cl = t >> 7, k = t & 127;
  const int c = blockIdx.x * 2 + cl;
  const float* A0 = ws;
  const float* A1 = ws + 16384;
  const float* A2 = ws + 27200;
  float v;
  if (k < 24) {
    v = A0[k * DIM + c];
  } else {
    float acc = 0.0f;
    const float* a1r = A1 + (k - 24) * 104;
    #pragma unroll 8
    for (int kk = 0; kk < 104; ++kk) acc = fmaf(a1r[kk], A0[(24 + kk) * DIM + c], acc);
    v = acc;
  }
  p1[k * 2 + cl] = v;
  __syncthreads();
  const int r = k;
  float m;
  if (r < 52) {
    m = p1[r * 2 + cl];
  } else {
    float acc = 0.0f;
    const float* a2r = A2 + (r - 52) * 76;
    #pragma unroll 8
    for (int kk = 0; kk < 76; ++kk) acc = fmaf(a2r[kk], p1[(52 + kk) * 2 + cl], acc);
    m = acc;
  }
  Mb[r * DIM + c] = f2bf(m);
}

// ---- K3: out = X @ M^T + bias (bf16 MFMA, B from L2-resident Mb, no LDS) ----
__global__ __launch_bounds__(256) void k_gemm(const float* __restrict__ X,
                                              const float* __restrict__ bias,
                                              const unsigned short* __restrict__ Mb,
                                              float* __restrict__ out) {
  const int lane = threadIdx.x & 63;
  const int wid  = threadIdx.x >> 6;           // 4 waves/block
  const int l15  = lane & 15, lhi = lane >> 4; // row-in-tile, k-quarter
  const int rowbase = blockIdx.x * 128 + wid * 32;

  f32x4 acc[2][8];
  #pragma unroll
  for (int m = 0; m < 2; ++m)
    #pragma unroll
    for (int n = 0; n < 8; ++n) acc[m][n] = (f32x4){0.f, 0.f, 0.f, 0.f};

  bf16x8 a[2][4];
  #pragma unroll
  for (int mt = 0; mt < 2; ++mt) {
    const float* xp = X + (rowbase + mt * 16 + l15) * DIM + lhi * 8;
    #pragma unroll
    for (int kt = 0; kt < 4; ++kt) {
      const f32x4 x0 = *(const f32x4*)(xp + kt * 32);
      const f32x4 x1 = *(const f32x4*)(xp + kt * 32 + 4);
      bf16x8 av;
      av[0] = (short)f2bf(x0[0]); av[1] = (short)f2bf(x0[1]);
      av[2] = (short)f2bf(x0[2]); av[3] = (short)f2bf(x0[3]);
      av[4] = (short)f2bf(x1[0]); av[5] = (short)f2bf(x1[1]);
      av[6] = (short)f2bf(x1[2]); av[7] = (short)f2bf(x1[3]);
      a[mt][kt] = av;
    }
  }

  #pragma unroll
  for (int kt = 0; kt < 4; ++kt) {
    #pragma unroll
    for (int n = 0; n < 8; ++n) {
      const bf16x8 b = *(const bf16x8*)(Mb + ((l15 + 16 * n) * DIM + kt * 32 + lhi * 8));
      acc[0][n] = __builtin_amdgcn_mfma_f32_16x16x32_bf16(a[0][kt], b, acc[0][n], 0, 0, 0);
      acc[1][n] = __builtin_amdgcn_mfma_f32_16x16x32_bf16(a[1][kt], b, acc[1][n], 0, 0, 0);
    }
  }

  #pragma unroll
  for (int n = 0; n < 8; ++n) {
    const float bs = bias[16 * n + l15];
    #pragma unroll
    for (int mt = 0; mt < 2; ++mt) {
      const int rb = rowbase + mt * 16 + lhi * 4;
      #pragma unroll
      for (int j = 0; j < 4; ++j)
        out[(rb + j) * DIM + 16 * n + l15] = acc[mt][n][j] + bs;
    }
  }
}

extern "C" void kernel_launch(void* const* d_in, const int* in_sizes, int n_in,
                              void* d_out, int out_size, void* d_ws, size_t ws_size,
                              hipStream_t stream) {
  const float* x      = (const float*)d_in[0];
  const float* angles = (const float*)d_in[1];
  const float* bias   = (const float*)d_in[2];
  float* out = (float*)d_out;
  float* ws  = (float*)d_ws;
  unsigned short* Mb = (unsigned short*)((char*)d_ws + 131904);

  k_build<<<3, 256, 0, stream>>>(angles, ws);
  k_combine<<<64, 256, 0, stream>>>(ws, Mb);
  k_gemm<<<1024, 256, 0, stream>>>(x, bias, Mb, out);
}

// Round 3
// 91.539 us; speedup vs baseline: 2.5631x; 1.4155x over previous
//
#include <hip/hip_runtime.h>
#include <hip/hip_bf16.h>

#define DIM 128
// 4 fan groups: [0,17) [17,38) [38,64) [64,127); T(i)=127i-i(i-1)/2
// rotations per group: 2023 / 2100 / 1989 / 2016
// ws layout (floats): A0@0 (128^2) A1@16384 (111^2) A2@28705 (90^2) A3@36805 (64^2) end 40901
// Mb (bf16 M row-major [128][128]) at byte 163616; total ws use 196384 B (proven budget).

typedef __attribute__((ext_vector_type(4))) float f32x4;
typedef __attribute__((ext_vector_type(8))) short bf16x8;

__device__ __forceinline__ unsigned short f2bf(float f) {
  union { float f; unsigned int u; } v; v.f = f;
  unsigned int u = v.u;
  return (unsigned short)((u + 0x7FFFu + ((u >> 16) & 1u)) >> 16);
}

// ---- register-resident group build: thread t owns column t of the group product ----
template<int LO, int NF, int N, int RB, int RE>
__device__ void build_group(const float* __restrict__ angles, float* __restrict__ A,
                            float4* __restrict__ cs) {
  const int t = threadIdx.x;
  // sincos prologue for this group's rotations -> pair-merged (c1,s1,c2,s2) stream in LDS
  for (int r0 = RB + t; r0 < RE; r0 += 256) {
    int i = (int)floorf((255.0f - sqrtf(65025.0f - 8.0f * (float)r0)) * 0.5f);
    if (i < 0) i = 0; if (i > 126) i = 126;
    while (127 * (i + 1) - ((i + 1) * i) / 2 <= r0) ++i;
    while (127 * i - (i * (i - 1)) / 2 > r0) --i;
    const int Ti = 127 * i - (i * (i - 1)) / 2;
    const int j  = i + 1 + (r0 - Ti);
    const int fl = i - LO, p = fl >> 1, sec = fl & 1;
    const int f1 = 2 * p;
    const int off = p * (N - p) + ((j - LO) - f1 - 1);
    float s, c; __sincosf(angles[r0], &s, &c);
    float2 v; v.x = c; v.y = s;
    *((float2*)&cs[off] + sec) = v;
  }
  __syncthreads();
  if (t >= N) return;

  float col[N];
  #pragma unroll
  for (int r = 0; r < N; ++r) col[r] = (r == t) ? 1.0f : 0.0f;

  constexpr int P = (NF + 1) / 2;   // odd NF: last pair's 2nd fan padded to identity (1,0)
  #pragma unroll
  for (int p = 0; p < P; ++p) {
    const int f1 = 2 * p;
    const float4 e0 = cs[p * (N - p)];
    float r1 = col[f1];
    const float rj = col[f1 + 1];
    float r2 = fmaf(e0.y, r1, e0.x * rj);
    r1 = fmaf(e0.x, r1, -(e0.y * rj));
    #pragma unroll
    for (int jl = f1 + 2; jl < N; ++jl) {
      const float4 e = cs[p * (N - p) + (jl - f1 - 1)];
      const float rv = col[jl];
      const float wv = fmaf(e.y, r1, e.x * rv);     // rot1 new row j
      r1 = fmaf(e.x, r1, -(e.y * rv));              // rot1 new row f1 (the 4-cyc chain)
      col[jl] = fmaf(e.w, r2, e.z * wv);            // rot2 new row j
      r2 = fmaf(e.z, r2, -(e.w * wv));              // rot2 new row f1+1
    }
    col[f1] = r1; col[f1 + 1] = r2;
  }
  #pragma unroll
  for (int r = 0; r < N; ++r) A[r * N + t] = col[r];   // coalesced across columns
}

__global__ __launch_bounds__(256, 1) void k_build(const float* __restrict__ angles,
                                                  float* __restrict__ ws) {
  __shared__ float4 cs[1104];        // 17.7 KB; init to identity for padded halves
  const int t = threadIdx.x;
  for (int k = t; k < 1104; k += 256) { float4 v; v.x = 1.f; v.y = 0.f; v.z = 1.f; v.w = 0.f; cs[k] = v; }
  __syncthreads();
  switch (blockIdx.x) {
    case 0: build_group<0, 17, 128,    0, 2023>(angles, ws,         cs); break;
    case 1: build_group<17, 21, 111, 2023, 4123>(angles, ws + 16384, cs); break;
    case 2: build_group<38, 26,  90, 4123, 6112>(angles, ws + 28705, cs); break;
    default: build_group<64, 63, 64, 6112, 8128>(angles, ws + 36805, cs); break;
  }
}

// ---- combine: column c of M = A3*A2*A1*A0*e_c via 4 chained matvecs ----
__global__ __launch_bounds__(128) void k_combine(const float* __restrict__ ws,
                                                 unsigned short* __restrict__ Mb) {
  __shared__ float x[DIM];
  const int c = blockIdx.x, r = threadIdx.x;
  x[r] = (r == c) ? 1.0f : 0.0f;
  __syncthreads();
  const int LOs[4]  = {0, 17, 38, 64};
  const int Ns[4]   = {128, 111, 90, 64};
  const int offs[4] = {0, 16384, 28705, 36805};
  #pragma unroll
  for (int g = 0; g < 4; ++g) {
    const int lo = LOs[g], n = Ns[g];
    float y;
    if (r >= lo) {
      const float* Ar = ws + offs[g] + (r - lo) * n;
      float acc = 0.0f;
      #pragma unroll 8
      for (int k = 0; k < n; ++k) acc = fmaf(Ar[k], x[lo + k], acc);
      y = acc;
    } else {
      y = x[r];
    }
    __syncthreads();
    x[r] = y;
    __syncthreads();
  }
  Mb[r * DIM + c] = f2bf(x[r]);
}

// ---- out = X @ M^T + bias (bf16 MFMA, B from L2-resident Mb, no LDS) ----
__global__ __launch_bounds__(256) void k_gemm(const float* __restrict__ X,
                                              const float* __restrict__ bias,
                                              const unsigned short* __restrict__ Mb,
                                              float* __restrict__ out) {
  const int lane = threadIdx.x & 63;
  const int wid  = threadIdx.x >> 6;           // 4 waves/block
  const int l15  = lane & 15, lhi = lane >> 4; // row-in-tile, k-quarter
  const int rowbase = blockIdx.x * 128 + wid * 32;

  f32x4 acc[2][8];
  #pragma unroll
  for (int m = 0; m < 2; ++m)
    #pragma unroll
    for (int n = 0; n < 8; ++n) acc[m][n] = (f32x4){0.f, 0.f, 0.f, 0.f};

  bf16x8 a[2][4];
  #pragma unroll
  for (int mt = 0; mt < 2; ++mt) {
    const float* xp = X + (rowbase + mt * 16 + l15) * DIM + lhi * 8;
    #pragma unroll
    for (int kt = 0; kt < 4; ++kt) {
      const f32x4 x0 = *(const f32x4*)(xp + kt * 32);
      const f32x4 x1 = *(const f32x4*)(xp + kt * 32 + 4);
      bf16x8 av;
      av[0] = (short)f2bf(x0[0]); av[1] = (short)f2bf(x0[1]);
      av[2] = (short)f2bf(x0[2]); av[3] = (short)f2bf(x0[3]);
      av[4] = (short)f2bf(x1[0]); av[5] = (short)f2bf(x1[1]);
      av[6] = (short)f2bf(x1[2]); av[7] = (short)f2bf(x1[3]);
      a[mt][kt] = av;
    }
  }

  #pragma unroll
  for (int kt = 0; kt < 4; ++kt) {
    #pragma unroll
    for (int n = 0; n < 8; ++n) {
      const bf16x8 b = *(const bf16x8*)(Mb + ((l15 + 16 * n) * DIM + kt * 32 + lhi * 8));
      acc[0][n] = __builtin_amdgcn_mfma_f32_16x16x32_bf16(a[0][kt], b, acc[0][n], 0, 0, 0);
      acc[1][n] = __builtin_amdgcn_mfma_f32_16x16x32_bf16(a[1][kt], b, acc[1][n], 0, 0, 0);
    }
  }

  #pragma unroll
  for (int n = 0; n < 8; ++n) {
    const float bs = bias[16 * n + l15];
    #pragma unroll
    for (int mt = 0; mt < 2; ++mt) {
      const int rb = rowbase + mt * 16 + lhi * 4;
      #pragma unroll
      for (int j = 0; j < 4; ++j)
        out[(rb + j) * DIM + 16 * n + l15] = acc[mt][n][j] + bs;
    }
  }
}

extern "C" void kernel_launch(void* const* d_in, const int* in_sizes, int n_in,
                              void* d_out, int out_size, void* d_ws, size_t ws_size,
                              hipStream_t stream) {
  const float* x      = (const float*)d_in[0];
  const float* angles = (const float*)d_in[1];
  const float* bias   = (const float*)d_in[2];
  float* out = (float*)d_out;
  float* ws  = (float*)d_ws;
  unsigned short* Mb = (unsigned short*)((char*)d_ws + 163616);

  k_build<<<4, 256, 0, stream>>>(angles, ws);
  k_combine<<<128, 128, 0, stream>>>(ws, Mb);
  k_gemm<<<1024, 256, 0, stream>>>(x, bias, Mb, out);
}